// Round 9
// baseline (741.224 us; speedup 1.0000x reference)
//
#include <hip/hip_runtime.h>

// MPDO open-boundary contraction — MX-scaled fp8 MFMA (32x32x64), pipelined.
// Per element: E0 = Lr·Lcᵀ; 62 steps E' = Σ_k Ar_kᵀ·E·Ac_k (×0.25 folded into
// packed Ac); rho = <E, Rr·Rcᵀ>; out = log(complex64(rho)) + 62·ln4.
//   P1: Tᵀ[l, jk] = Σ_i Eᵀ[l,i]·Ar[i,jk]   — one-shot mfma_scale (K=64 = full i)
//   P2: E'[j, m]  = Σ_kl T[j,kl]·Ac[kl,m]  — 4-chain mfma_scale
// Round-9 change vs round-8 (561 µs, MfmaUtil 46, Occ 42, VGPR 60):
//   LDS shrink: TL strides JSB 392→264, KSB 96→64. Identical bank residues
//   (98 dw ≡ 66 dw ≡ 2 mod 32 → all read/write patterns stay 2-way-free),
//   but LDS drops 29.7→21.5 KB → ~7 blocks/CU by LDS (was ~4; occupancy was
//   LDS-capped across rounds 6-8). __launch_bounds__(256,6): VGPR cap 85
//   (observed use 60). More resident blocks cover the per-step barrier +
//   dependent-chain stalls that MfmaUtil=46% exposes.
// Fragments: A/B m|n = lane&31, k = 32*(lane>>5)+byte; C/D col=lane&31,
// row=(reg&3)+8*(reg>>2)+4*(lane>>5). Scales = 1.0 (0x7f).

#define NSITES 62
#define PI_F   3.14159265358979323846f
#define LN4_F  1.38629436111989061883f
#define ETS 72     // ET row stride, bytes (18 dw ≡ 2 mod 4 -> conflict-free b64)
#define KSB 64     // TL k stride, bytes (payload, no pad needed)
#define JSB 264    // TL j stride, bytes = 4*KSB + 8 pad (66 dw ≡ 2 mod 32)

typedef __attribute__((ext_vector_type(8)))  int   v8i;
typedef __attribute__((ext_vector_type(16))) float f32x16;

__device__ __forceinline__ float clamp8(float v) {
    return fminf(fmaxf(v, -448.f), 448.f);
}
// clamped pack (prepass / init — off critical path)
__device__ __forceinline__ int pk4c(float a, float b, float c, float d) {
    int r = __builtin_amdgcn_cvt_pk_fp8_f32(clamp8(a), clamp8(b), 0, false);
    r     = __builtin_amdgcn_cvt_pk_fp8_f32(clamp8(c), clamp8(d), r, true);
    return r;
}
// fast pack (main loop): values provably in fp8 range (growth cancelled by 0.25)
__device__ __forceinline__ int pk4(float a, float b, float c, float d) {
    int r = __builtin_amdgcn_cvt_pk_fp8_f32(a, b, 0, false);
    r     = __builtin_amdgcn_cvt_pk_fp8_f32(c, d, r, true);
    return r;
}
// 32-byte LDS fragment load as 4×b64 (8-aligned, conflict-free strides)
__device__ __forceinline__ v8i lds32(const unsigned char* p) {
    union { v8i v; unsigned long long u[4]; } r;
    r.u[0] = *(const unsigned long long*)(p);
    r.u[1] = *(const unsigned long long*)(p + 8);
    r.u[2] = *(const unsigned long long*)(p + 16);
    r.u[3] = *(const unsigned long long*)(p + 24);
    return r.v;
}
__device__ __forceinline__ f32x16 mfma_mx(v8i a, v8i b, f32x16 c) {
    // cbsz=0 (A fp8 e4m3), blgp=0 (B fp8), scales = 1.0 (0x7f bytes)
    return __builtin_amdgcn_mfma_scale_f32_32x32x64_f8f6f4(
        a, b, c, 0, 0, 0, 0x7f7f7f7f, 0, 0x7f7f7f7f);
}

// ---------------- prepass: middle (fp32) -> 32 B/lane fp8 fragments ----------------
// a1f: byte(sv, jt, lane, idx) = mid[sv][i = 32*(lane>>5)+idx][jk = jt*32+(lane&31)]
// b2f: byte(sv, mt*4+q, lane, idx) = 0.25*mid[sv][l = 32*(lane>>5)+idx][(mt*32+(lane&31))*4+q]
__global__ void mpdo_prepass(const float* __restrict__ mid,
                             unsigned char* __restrict__ a1f,
                             unsigned char* __restrict__ b2f)
{
    const int bb  = blockIdx.x;          // 0..1983
    const int buf = bb / 992;
    const int rem = bb % 992;
    const int sv  = rem >> 3;
    const int rg  = rem & 7;
    const int row = rg * 4 + (threadIdx.x >> 6);   // 0..31
    const int lane = threadIdx.x & 63;
    const int hh = lane >> 5, l5 = lane & 31;
    const int grp = row >> 2, seg = row & 3;       // grp: jt or mt*4+q
    const float* m0 = mid + (size_t)sv * 16384;

    float v[8];
    if (buf == 0) {
        const int jk = grp * 32 + l5;
        #pragma unroll
        for (int jj = 0; jj < 8; ++jj) {
            const int i = 32 * hh + 8 * seg + jj;
            v[jj] = m0[i * 256 + jk];
        }
    } else {
        const int mt = grp >> 2, q = grp & 3;
        const int col = (mt * 32 + l5) * 4 + q;
        #pragma unroll
        for (int jj = 0; jj < 8; ++jj) {
            const int l = 32 * hh + 8 * seg + jj;
            v[jj] = 0.25f * m0[l * 256 + col];     // fold per-step rescale
        }
    }
    int2 d;
    d.x = pk4c(v[0], v[1], v[2], v[3]);
    d.y = pk4c(v[4], v[5], v[6], v[7]);
    unsigned char* base = (buf == 0 ? a1f : b2f);
    *(int2*)(base + ((size_t)(sv * 8 + grp) * 64 + lane) * 32 + seg * 8) = d;
}

// ---------------- main kernel: 1 block per batch element ----------------
__global__ __launch_bounds__(256, 6)
void mpdo_mx(const int* __restrict__ x,
             const float* __restrict__ left,
             const float* __restrict__ right,
             const unsigned char* __restrict__ a1f,
             const unsigned char* __restrict__ b2f,
             float* __restrict__ out)
{
    __shared__ __align__(16) unsigned char ET[64 * ETS];  // ET[l][i] = E[i][l], fp8
    __shared__ __align__(16) unsigned char TL[64 * JSB];  // TL[j][k][l] = T, fp8
    __shared__ float red[4];

    const int t    = threadIdx.x;
    const int lane = t & 63;
    const int ln   = t & 31;
    const int h    = (t >> 5) & 1;
    const int w    = t >> 6;
    const int b    = blockIdx.x;
    const int* xb  = x + b * 128;

    // ---- init ET[l][i] = fp8( sum_k Lr[i,k]*Lc[l,k] ) ----
    {
        const int r0 = xb[0], c0 = xb[64];
        const int l = t >> 2, cq = t & 3;
        const float4 lc = *(const float4*)(left + c0 * 256 + l * 4);
        #pragma unroll
        for (int ib = 0; ib < 4; ++ib) {
            float vv[4];
            #pragma unroll
            for (int u = 0; u < 4; ++u) {
                const int i = cq * 16 + ib * 4 + u;
                const float4 lr = *(const float4*)(left + r0 * 256 + i * 4);
                vv[u] = lr.x * lc.x + lr.y * lc.y + lr.z * lc.z + lr.w * lc.w;
            }
            *(int*)&ET[l * ETS + cq * 16 + ib * 4] = pk4c(vv[0], vv[1], vv[2], vv[3]);
        }
    }

    const int jt2 = w >> 1;   // phase-2 j-tile
    const int mt  = w & 1;    // phase-2 m-tile

    // const-zero C operand — lives across the loop, never written
    f32x16 z16;
    #pragma unroll
    for (int r = 0; r < 16; ++r) z16[r] = 0.f;

    // prefetch P1 B-operands for s=0
    v8i bP1a, bP1b;
    {
        const unsigned char* A1 = a1f + (size_t)(0 * 2 + xb[1]) * 16384;
        bP1a = *(const v8i*)(A1 + ((size_t)(2 * w + 0) * 64 + lane) * 32);
        bP1b = *(const v8i*)(A1 + ((size_t)(2 * w + 1) * 64 + lane) * 32);
    }
    __syncthreads();

    f32x16 acc2;

    #pragma unroll 1
    for (int s = 0; s < NSITES; ++s) {
        // ---- issue this step's P2 loads (in flight through phase 1) ----
        const unsigned char* B2 = b2f + (size_t)(s * 2 + xb[65 + s]) * 16384;
        v8i bP2[4];
        #pragma unroll
        for (int q = 0; q < 4; ++q)
            bP2[q] = *(const v8i*)(B2 + ((size_t)(mt * 4 + q) * 64 + lane) * 32);

        // ---- issue next step's P1 loads (in flight through this whole step) ----
        const int sn = (s + 1 < NSITES) ? s + 1 : s;
        const unsigned char* A1n = a1f + (size_t)(sn * 2 + xb[1 + sn]) * 16384;
        v8i nb0 = *(const v8i*)(A1n + ((size_t)(2 * w + 0) * 64 + lane) * 32);
        v8i nb1 = *(const v8i*)(A1n + ((size_t)(2 * w + 1) * 64 + lane) * 32);

        // ---- phase 1 (two jl-halves) ----
        const v8i aF0 = lds32(&ET[(0  + ln) * ETS + 32 * h]);
        const v8i aF1 = lds32(&ET[(32 + ln) * ETS + 32 * h]);
        {
            const f32x16 t0 = mfma_mx(aF0, bP1a, z16);
            const f32x16 t1 = mfma_mx(aF1, bP1a, z16);
            const int jk = (2 * w + 0) * 32 + ln;
            const unsigned base = (jk >> 2) * JSB + (jk & 3) * KSB + 4 * h;
            #pragma unroll
            for (int g = 0; g < 4; ++g) {
                *(int*)&TL[base + 8 * g]      = pk4(t0[4*g], t0[4*g+1], t0[4*g+2], t0[4*g+3]);
                *(int*)&TL[base + 32 + 8 * g] = pk4(t1[4*g], t1[4*g+1], t1[4*g+2], t1[4*g+3]);
            }
        }
        {
            const f32x16 t0 = mfma_mx(aF0, bP1b, z16);
            const f32x16 t1 = mfma_mx(aF1, bP1b, z16);
            const int jk = (2 * w + 1) * 32 + ln;
            const unsigned base = (jk >> 2) * JSB + (jk & 3) * KSB + 4 * h;
            #pragma unroll
            for (int g = 0; g < 4; ++g) {
                *(int*)&TL[base + 8 * g]      = pk4(t0[4*g], t0[4*g+1], t0[4*g+2], t0[4*g+3]);
                *(int*)&TL[base + 32 + 8 * g] = pk4(t1[4*g], t1[4*g+1], t1[4*g+2], t1[4*g+3]);
            }
        }
        __syncthreads();

        // ---- phase 2: E'[j,m] = Σ_q Σ_l T[j,q,l]·(0.25·Ac)[l, m*4+q] ----
        acc2 = mfma_mx(lds32(&TL[(jt2 * 32 + ln) * JSB + 0 * KSB + 32 * h]), bP2[0], z16);
        #pragma unroll
        for (int q = 1; q < 4; ++q)
            acc2 = mfma_mx(lds32(&TL[(jt2 * 32 + ln) * JSB + q * KSB + 32 * h]), bP2[q], acc2);

        if (s < NSITES - 1) {
            // write E' back: ET[m][j] = E'[j][m], 4 fp8 per b32
            const unsigned base = (mt * 32 + ln) * ETS + jt2 * 32 + 4 * h;
            #pragma unroll
            for (int g = 0; g < 4; ++g)
                *(int*)&ET[base + 8 * g] =
                    pk4(acc2[4 * g], acc2[4 * g + 1], acc2[4 * g + 2], acc2[4 * g + 3]);
        }
        __syncthreads();

        bP1a = nb0; bP1b = nb1;
    }

    // ---- final: rho = sum E_final[j,m] * R[j,m], R = Rr·Rcᵀ (fp32) ----
    {
        const int rR = xb[63], cR = xb[127];
        const int m = mt * 32 + ln;
        const float4 rc = *(const float4*)(right + cR * 256 + m * 4);
        float partial = 0.f;
        #pragma unroll
        for (int r = 0; r < 16; ++r) {
            const int j = jt2 * 32 + (r & 3) + 8 * (r >> 2) + 4 * h;
            const float4 rr = *(const float4*)(right + rR * 256 + j * 4);
            const float Rv = rr.x * rc.x + rr.y * rc.y + rr.z * rc.z + rr.w * rc.w;
            partial += acc2[r] * Rv;
        }
        #pragma unroll
        for (int off = 32; off > 0; off >>= 1)
            partial += __shfl_down(partial, off, 64);
        if (lane == 0) red[w] = partial;
        __syncthreads();
        if (t == 0) {
            const float rho = red[0] + red[1] + red[2] + red[3];
            out[2 * b + 0] = logf(fabsf(rho)) + (float)NSITES * LN4_F;
            out[2 * b + 1] = (rho < 0.f) ? PI_F : 0.f;
        }
    }
}

// ---------------- fp32 fallback if ws too small ----------------
__global__ __launch_bounds__(256, 3)
void mpdo_fp32(const int* __restrict__ x, const float* __restrict__ left,
               const float* __restrict__ right, const float* __restrict__ middle,
               float* __restrict__ out)
{
    __shared__ float ETf[64 * 64];
    __shared__ float TRI[32 * 256];
    __shared__ float red[4];
    const int t = threadIdx.x, lane = t & 63, q = t >> 6, b = blockIdx.x;
    const int* xb = x + b * 128;
    {
        const int r0 = xb[0], c0 = xb[64];
        const float4 lr = *(const float4*)(left + r0 * 256 + lane * 4);
        #pragma unroll
        for (int u = 0; u < 16; ++u) {
            const int bb = q * 16 + u;
            const float4 lc = *(const float4*)(left + c0 * 256 + bb * 4);
            ETf[bb * 64 + lane] = lr.x * lc.x + lr.y * lc.y + lr.z * lc.z + lr.w * lc.w;
        }
    }
    __syncthreads();
    float acc2[16];
    for (int s = 0; s < NSITES; ++s) {
        const int r = xb[1 + s], c = xb[65 + s];
        const float* Ar = middle + (size_t)s * 32768 + (size_t)r * 16384;
        const float* Ac = middle + (size_t)s * 32768 + (size_t)c * 16384;
        #pragma unroll
        for (int u = 0; u < 16; ++u) acc2[u] = 0.f;
        float acc[4][16];
        #pragma unroll
        for (int j = 0; j < 4; ++j)
            #pragma unroll
            for (int u = 0; u < 16; ++u) acc[j][u] = 0.f;
        #pragma unroll 1
        for (int i4 = 0; i4 < 16; ++i4) {
            const float4 a0 = *(const float4*)(Ar + (i4 * 4 + 0) * 256 + lane * 4);
            const float4 a1 = *(const float4*)(Ar + (i4 * 4 + 1) * 256 + lane * 4);
            const float4 a2 = *(const float4*)(Ar + (i4 * 4 + 2) * 256 + lane * 4);
            const float4 a3 = *(const float4*)(Ar + (i4 * 4 + 3) * 256 + lane * 4);
            #pragma unroll
            for (int hh = 0; hh < 2; ++hh) {
                #pragma unroll
                for (int lp = 0; lp < 8; ++lp) {
                    const int lg = hh * 32 + q * 8 + lp;
                    const float4 e = *(const float4*)&ETf[lg * 64 + i4 * 4];
                    const int li = hh * 8 + lp;
                    acc[0][li] += a0.x * e.x + a1.x * e.y + a2.x * e.z + a3.x * e.w;
                    acc[1][li] += a0.y * e.x + a1.y * e.y + a2.y * e.z + a3.y * e.w;
                    acc[2][li] += a0.z * e.x + a1.z * e.y + a2.z * e.z + a3.z * e.w;
                    acc[3][li] += a0.w * e.x + a1.w * e.y + a2.w * e.z + a3.w * e.w;
                }
            }
        }
        #pragma unroll 1
        for (int hh = 0; hh < 2; ++hh) {
            #pragma unroll
            for (int lp = 0; lp < 8; ++lp) {
                const int li = hh * 8 + lp;
                const float4 v = make_float4(acc[0][li], acc[1][li], acc[2][li], acc[3][li]);
                *(float4*)&TRI[(q * 8 + lp) * 256 + lane * 4] = v;
            }
            __syncthreads();
            const float* Acb = Ac + hh * 32 * 256 + q * 64;
            #pragma unroll 1
            for (int ll = 0; ll < 32; ++ll) {
                const float4 tr = *(const float4*)&TRI[ll * 256 + lane * 4];
                const float* bp = Acb + ll * 256;
                #pragma unroll
                for (int u = 0; u < 16; ++u) {
                    const float4 cc = *(const float4*)(bp + u * 4);
                    acc2[u] += tr.x * cc.x + tr.y * cc.y + tr.z * cc.z + tr.w * cc.w;
                }
            }
            if (hh == 1) {
                #pragma unroll
                for (int u = 0; u < 16; ++u) acc2[u] *= 0.25f;
                if (s < NSITES - 1) {
                    #pragma unroll
                    for (int u = 0; u < 16; ++u) ETf[(q * 16 + u) * 64 + lane] = acc2[u];
                }
            }
            __syncthreads();
        }
    }
    {
        const int rR = xb[63], cR = xb[127];
        const float4 rr = *(const float4*)(right + rR * 256 + lane * 4);
        float partial = 0.f;
        #pragma unroll
        for (int u = 0; u < 16; ++u) {
            const int m = q * 16 + u;
            const float4 rcv = *(const float4*)(right + cR * 256 + m * 4);
            const float rv = rr.x * rcv.x + rr.y * rcv.y + rr.z * rcv.z + rr.w * rcv.w;
            partial += acc2[u] * rv;
        }
        #pragma unroll
        for (int off = 32; off > 0; off >>= 1)
            partial += __shfl_down(partial, off, 64);
        if (lane == 0) red[q] = partial;
        __syncthreads();
        if (t == 0) {
            const float rho = red[0] + red[1] + red[2] + red[3];
            out[2 * b + 0] = logf(fabsf(rho)) + (float)NSITES * LN4_F;
            out[2 * b + 1] = (rho < 0.f) ? PI_F : 0.f;
        }
    }
}

extern "C" void kernel_launch(void* const* d_in, const int* in_sizes, int n_in,
                              void* d_out, int out_size, void* d_ws, size_t ws_size,
                              hipStream_t stream) {
    const int*   x      = (const int*)  d_in[0];
    const float* left   = (const float*)d_in[1];
    const float* right  = (const float*)d_in[2];
    const float* middle = (const float*)d_in[3];
    float* out = (float*)d_out;

    const size_t A1_BYTES = (size_t)124 * 16384;   // 1.98 MB per operand buffer
    if (ws_size >= 2 * A1_BYTES) {
        unsigned char* a1f = (unsigned char*)d_ws;
        unsigned char* b2f = a1f + A1_BYTES;
        mpdo_prepass<<<dim3(1984), dim3(256), 0, stream>>>(middle, a1f, b2f);
        mpdo_mx<<<dim3(4096), dim3(256), 0, stream>>>(x, left, right, a1f, b2f, out);
    } else {
        mpdo_fp32<<<dim3(4096), dim3(256), 0, stream>>>(x, left, right, middle, out);
    }
}

// Round 10
// 569.700 us; speedup vs baseline: 1.3011x; 1.3011x over previous
//
#include <hip/hip_runtime.h>

// MPDO open-boundary contraction — MX-scaled fp8 MFMA (32x32x64), pipelined.
// Per element: E0 = Lr·Lcᵀ; 62 steps E' = Σ_k Ar_kᵀ·E·Ac_k (×0.25 folded into
// packed Ac); rho = <E, Rr·Rcᵀ>; out = log(complex64(rho)) + 62·ln4.
//   P1: Tᵀ[l, jk] = Σ_i Eᵀ[l,i]·Ar[i,jk]   — one-shot mfma_scale (K=64 = full i)
//   P2: E'[j, m]  = Σ_kl T[j,kl]·Ac[kl,m]  — 4-chain mfma_scale
// Round-10 = round-9's LDS shrink (validated: Occ 42→63%) + round-8's register
// budget (validated: no spill). Round-9's (256,6) capped VGPRs at 85 < ~110
// live prefetch bytes → scratch spill (WRITE_SIZE 69 MB, dur 741). (256,4)
// gives cap 128; observed use ≈60, spill-free. LDS 21.5 KB → 7 blocks/CU.
// LDS strides: ET row 72 B (18 dw ≡ 2 mod 4), TL j 264 B (66 dw ≡ 2 mod 32),
// k 64 B — all read/write patterns at the 2-access/bank hardware minimum.
// Fragments: A/B m|n = lane&31, k = 32*(lane>>5)+byte; C/D col=lane&31,
// row=(reg&3)+8*(reg>>2)+4*(lane>>5). Scales = 1.0 (0x7f).

#define NSITES 62
#define PI_F   3.14159265358979323846f
#define LN4_F  1.38629436111989061883f
#define ETS 72     // ET row stride, bytes
#define KSB 64     // TL k stride, bytes
#define JSB 264    // TL j stride, bytes = 4*KSB + 8 pad

typedef __attribute__((ext_vector_type(8)))  int   v8i;
typedef __attribute__((ext_vector_type(16))) float f32x16;

__device__ __forceinline__ float clamp8(float v) {
    return fminf(fmaxf(v, -448.f), 448.f);
}
// clamped pack (prepass / init — off critical path)
__device__ __forceinline__ int pk4c(float a, float b, float c, float d) {
    int r = __builtin_amdgcn_cvt_pk_fp8_f32(clamp8(a), clamp8(b), 0, false);
    r     = __builtin_amdgcn_cvt_pk_fp8_f32(clamp8(c), clamp8(d), r, true);
    return r;
}
// fast pack (main loop): values provably in fp8 range (growth cancelled by 0.25)
__device__ __forceinline__ int pk4(float a, float b, float c, float d) {
    int r = __builtin_amdgcn_cvt_pk_fp8_f32(a, b, 0, false);
    r     = __builtin_amdgcn_cvt_pk_fp8_f32(c, d, r, true);
    return r;
}
// 32-byte LDS fragment load as 4×b64 (8-aligned, conflict-free strides)
__device__ __forceinline__ v8i lds32(const unsigned char* p) {
    union { v8i v; unsigned long long u[4]; } r;
    r.u[0] = *(const unsigned long long*)(p);
    r.u[1] = *(const unsigned long long*)(p + 8);
    r.u[2] = *(const unsigned long long*)(p + 16);
    r.u[3] = *(const unsigned long long*)(p + 24);
    return r.v;
}
__device__ __forceinline__ f32x16 mfma_mx(v8i a, v8i b, f32x16 c) {
    // cbsz=0 (A fp8 e4m3), blgp=0 (B fp8), scales = 1.0 (0x7f bytes)
    return __builtin_amdgcn_mfma_scale_f32_32x32x64_f8f6f4(
        a, b, c, 0, 0, 0, 0x7f7f7f7f, 0, 0x7f7f7f7f);
}

// ---------------- prepass: middle (fp32) -> 32 B/lane fp8 fragments ----------------
// a1f: byte(sv, jt, lane, idx) = mid[sv][i = 32*(lane>>5)+idx][jk = jt*32+(lane&31)]
// b2f: byte(sv, mt*4+q, lane, idx) = 0.25*mid[sv][l = 32*(lane>>5)+idx][(mt*32+(lane&31))*4+q]
__global__ void mpdo_prepass(const float* __restrict__ mid,
                             unsigned char* __restrict__ a1f,
                             unsigned char* __restrict__ b2f)
{
    const int bb  = blockIdx.x;          // 0..1983
    const int buf = bb / 992;
    const int rem = bb % 992;
    const int sv  = rem >> 3;
    const int rg  = rem & 7;
    const int row = rg * 4 + (threadIdx.x >> 6);   // 0..31
    const int lane = threadIdx.x & 63;
    const int hh = lane >> 5, l5 = lane & 31;
    const int grp = row >> 2, seg = row & 3;       // grp: jt or mt*4+q
    const float* m0 = mid + (size_t)sv * 16384;

    float v[8];
    if (buf == 0) {
        const int jk = grp * 32 + l5;
        #pragma unroll
        for (int jj = 0; jj < 8; ++jj) {
            const int i = 32 * hh + 8 * seg + jj;
            v[jj] = m0[i * 256 + jk];
        }
    } else {
        const int mt = grp >> 2, q = grp & 3;
        const int col = (mt * 32 + l5) * 4 + q;
        #pragma unroll
        for (int jj = 0; jj < 8; ++jj) {
            const int l = 32 * hh + 8 * seg + jj;
            v[jj] = 0.25f * m0[l * 256 + col];     // fold per-step rescale
        }
    }
    int2 d;
    d.x = pk4c(v[0], v[1], v[2], v[3]);
    d.y = pk4c(v[4], v[5], v[6], v[7]);
    unsigned char* base = (buf == 0 ? a1f : b2f);
    *(int2*)(base + ((size_t)(sv * 8 + grp) * 64 + lane) * 32 + seg * 8) = d;
}

// ---------------- main kernel: 1 block per batch element ----------------
__global__ __launch_bounds__(256, 4)
void mpdo_mx(const int* __restrict__ x,
             const float* __restrict__ left,
             const float* __restrict__ right,
             const unsigned char* __restrict__ a1f,
             const unsigned char* __restrict__ b2f,
             float* __restrict__ out)
{
    __shared__ __align__(16) unsigned char ET[64 * ETS];  // ET[l][i] = E[i][l], fp8
    __shared__ __align__(16) unsigned char TL[64 * JSB];  // TL[j][k][l] = T, fp8
    __shared__ float red[4];

    const int t    = threadIdx.x;
    const int lane = t & 63;
    const int ln   = t & 31;
    const int h    = (t >> 5) & 1;
    const int w    = t >> 6;
    const int b    = blockIdx.x;
    const int* xb  = x + b * 128;

    // ---- init ET[l][i] = fp8( sum_k Lr[i,k]*Lc[l,k] ) ----
    {
        const int r0 = xb[0], c0 = xb[64];
        const int l = t >> 2, cq = t & 3;
        const float4 lc = *(const float4*)(left + c0 * 256 + l * 4);
        #pragma unroll
        for (int ib = 0; ib < 4; ++ib) {
            float vv[4];
            #pragma unroll
            for (int u = 0; u < 4; ++u) {
                const int i = cq * 16 + ib * 4 + u;
                const float4 lr = *(const float4*)(left + r0 * 256 + i * 4);
                vv[u] = lr.x * lc.x + lr.y * lc.y + lr.z * lc.z + lr.w * lc.w;
            }
            *(int*)&ET[l * ETS + cq * 16 + ib * 4] = pk4c(vv[0], vv[1], vv[2], vv[3]);
        }
    }

    const int jt2 = w >> 1;   // phase-2 j-tile
    const int mt  = w & 1;    // phase-2 m-tile

    // const-zero C operand — lives across the loop, never written
    f32x16 z16;
    #pragma unroll
    for (int r = 0; r < 16; ++r) z16[r] = 0.f;

    // prefetch P1 B-operands for s=0
    v8i bP1a, bP1b;
    {
        const unsigned char* A1 = a1f + (size_t)(0 * 2 + xb[1]) * 16384;
        bP1a = *(const v8i*)(A1 + ((size_t)(2 * w + 0) * 64 + lane) * 32);
        bP1b = *(const v8i*)(A1 + ((size_t)(2 * w + 1) * 64 + lane) * 32);
    }
    __syncthreads();

    f32x16 acc2;

    #pragma unroll 1
    for (int s = 0; s < NSITES; ++s) {
        // ---- issue this step's P2 loads (in flight through phase 1) ----
        const unsigned char* B2 = b2f + (size_t)(s * 2 + xb[65 + s]) * 16384;
        v8i bP2[4];
        #pragma unroll
        for (int q = 0; q < 4; ++q)
            bP2[q] = *(const v8i*)(B2 + ((size_t)(mt * 4 + q) * 64 + lane) * 32);

        // ---- issue next step's P1 loads (in flight through this whole step) ----
        const int sn = (s + 1 < NSITES) ? s + 1 : s;
        const unsigned char* A1n = a1f + (size_t)(sn * 2 + xb[1 + sn]) * 16384;
        v8i nb0 = *(const v8i*)(A1n + ((size_t)(2 * w + 0) * 64 + lane) * 32);
        v8i nb1 = *(const v8i*)(A1n + ((size_t)(2 * w + 1) * 64 + lane) * 32);

        // ---- phase 1 (two jl-halves) ----
        const v8i aF0 = lds32(&ET[(0  + ln) * ETS + 32 * h]);
        const v8i aF1 = lds32(&ET[(32 + ln) * ETS + 32 * h]);
        {
            const f32x16 t0 = mfma_mx(aF0, bP1a, z16);
            const f32x16 t1 = mfma_mx(aF1, bP1a, z16);
            const int jk = (2 * w + 0) * 32 + ln;
            const unsigned base = (jk >> 2) * JSB + (jk & 3) * KSB + 4 * h;
            #pragma unroll
            for (int g = 0; g < 4; ++g) {
                *(int*)&TL[base + 8 * g]      = pk4(t0[4*g], t0[4*g+1], t0[4*g+2], t0[4*g+3]);
                *(int*)&TL[base + 32 + 8 * g] = pk4(t1[4*g], t1[4*g+1], t1[4*g+2], t1[4*g+3]);
            }
        }
        {
            const f32x16 t0 = mfma_mx(aF0, bP1b, z16);
            const f32x16 t1 = mfma_mx(aF1, bP1b, z16);
            const int jk = (2 * w + 1) * 32 + ln;
            const unsigned base = (jk >> 2) * JSB + (jk & 3) * KSB + 4 * h;
            #pragma unroll
            for (int g = 0; g < 4; ++g) {
                *(int*)&TL[base + 8 * g]      = pk4(t0[4*g], t0[4*g+1], t0[4*g+2], t0[4*g+3]);
                *(int*)&TL[base + 32 + 8 * g] = pk4(t1[4*g], t1[4*g+1], t1[4*g+2], t1[4*g+3]);
            }
        }
        __syncthreads();

        // ---- phase 2: E'[j,m] = Σ_q Σ_l T[j,q,l]·(0.25·Ac)[l, m*4+q] ----
        acc2 = mfma_mx(lds32(&TL[(jt2 * 32 + ln) * JSB + 0 * KSB + 32 * h]), bP2[0], z16);
        #pragma unroll
        for (int q = 1; q < 4; ++q)
            acc2 = mfma_mx(lds32(&TL[(jt2 * 32 + ln) * JSB + q * KSB + 32 * h]), bP2[q], acc2);

        if (s < NSITES - 1) {
            // write E' back: ET[m][j] = E'[j][m], 4 fp8 per b32
            const unsigned base = (mt * 32 + ln) * ETS + jt2 * 32 + 4 * h;
            #pragma unroll
            for (int g = 0; g < 4; ++g)
                *(int*)&ET[base + 8 * g] =
                    pk4(acc2[4 * g], acc2[4 * g + 1], acc2[4 * g + 2], acc2[4 * g + 3]);
        }
        __syncthreads();

        bP1a = nb0; bP1b = nb1;
    }

    // ---- final: rho = sum E_final[j,m] * R[j,m], R = Rr·Rcᵀ (fp32) ----
    {
        const int rR = xb[63], cR = xb[127];
        const int m = mt * 32 + ln;
        const float4 rc = *(const float4*)(right + cR * 256 + m * 4);
        float partial = 0.f;
        #pragma unroll
        for (int r = 0; r < 16; ++r) {
            const int j = jt2 * 32 + (r & 3) + 8 * (r >> 2) + 4 * h;
            const float4 rr = *(const float4*)(right + rR * 256 + j * 4);
            const float Rv = rr.x * rc.x + rr.y * rc.y + rr.z * rc.z + rr.w * rc.w;
            partial += acc2[r] * Rv;
        }
        #pragma unroll
        for (int off = 32; off > 0; off >>= 1)
            partial += __shfl_down(partial, off, 64);
        if (lane == 0) red[w] = partial;
        __syncthreads();
        if (t == 0) {
            const float rho = red[0] + red[1] + red[2] + red[3];
            out[2 * b + 0] = logf(fabsf(rho)) + (float)NSITES * LN4_F;
            out[2 * b + 1] = (rho < 0.f) ? PI_F : 0.f;
        }
    }
}

// ---------------- fp32 fallback if ws too small ----------------
__global__ __launch_bounds__(256, 3)
void mpdo_fp32(const int* __restrict__ x, const float* __restrict__ left,
               const float* __restrict__ right, const float* __restrict__ middle,
               float* __restrict__ out)
{
    __shared__ float ETf[64 * 64];
    __shared__ float TRI[32 * 256];
    __shared__ float red[4];
    const int t = threadIdx.x, lane = t & 63, q = t >> 6, b = blockIdx.x;
    const int* xb = x + b * 128;
    {
        const int r0 = xb[0], c0 = xb[64];
        const float4 lr = *(const float4*)(left + r0 * 256 + lane * 4);
        #pragma unroll
        for (int u = 0; u < 16; ++u) {
            const int bb = q * 16 + u;
            const float4 lc = *(const float4*)(left + c0 * 256 + bb * 4);
            ETf[bb * 64 + lane] = lr.x * lc.x + lr.y * lc.y + lr.z * lc.z + lr.w * lc.w;
        }
    }
    __syncthreads();
    float acc2[16];
    for (int s = 0; s < NSITES; ++s) {
        const int r = xb[1 + s], c = xb[65 + s];
        const float* Ar = middle + (size_t)s * 32768 + (size_t)r * 16384;
        const float* Ac = middle + (size_t)s * 32768 + (size_t)c * 16384;
        #pragma unroll
        for (int u = 0; u < 16; ++u) acc2[u] = 0.f;
        float acc[4][16];
        #pragma unroll
        for (int j = 0; j < 4; ++j)
            #pragma unroll
            for (int u = 0; u < 16; ++u) acc[j][u] = 0.f;
        #pragma unroll 1
        for (int i4 = 0; i4 < 16; ++i4) {
            const float4 a0 = *(const float4*)(Ar + (i4 * 4 + 0) * 256 + lane * 4);
            const float4 a1 = *(const float4*)(Ar + (i4 * 4 + 1) * 256 + lane * 4);
            const float4 a2 = *(const float4*)(Ar + (i4 * 4 + 2) * 256 + lane * 4);
            const float4 a3 = *(const float4*)(Ar + (i4 * 4 + 3) * 256 + lane * 4);
            #pragma unroll
            for (int hh = 0; hh < 2; ++hh) {
                #pragma unroll
                for (int lp = 0; lp < 8; ++lp) {
                    const int lg = hh * 32 + q * 8 + lp;
                    const float4 e = *(const float4*)&ETf[lg * 64 + i4 * 4];
                    const int li = hh * 8 + lp;
                    acc[0][li] += a0.x * e.x + a1.x * e.y + a2.x * e.z + a3.x * e.w;
                    acc[1][li] += a0.y * e.x + a1.y * e.y + a2.y * e.z + a3.y * e.w;
                    acc[2][li] += a0.z * e.x + a1.z * e.y + a2.z * e.z + a3.z * e.w;
                    acc[3][li] += a0.w * e.x + a1.w * e.y + a2.w * e.z + a3.w * e.w;
                }
            }
        }
        #pragma unroll 1
        for (int hh = 0; hh < 2; ++hh) {
            #pragma unroll
            for (int lp = 0; lp < 8; ++lp) {
                const int li = hh * 8 + lp;
                const float4 v = make_float4(acc[0][li], acc[1][li], acc[2][li], acc[3][li]);
                *(float4*)&TRI[(q * 8 + lp) * 256 + lane * 4] = v;
            }
            __syncthreads();
            const float* Acb = Ac + hh * 32 * 256 + q * 64;
            #pragma unroll 1
            for (int ll = 0; ll < 32; ++ll) {
                const float4 tr = *(const float4*)&TRI[ll * 256 + lane * 4];
                const float* bp = Acb + ll * 256;
                #pragma unroll
                for (int u = 0; u < 16; ++u) {
                    const float4 cc = *(const float4*)(bp + u * 4);
                    acc2[u] += tr.x * cc.x + tr.y * cc.y + tr.z * cc.z + tr.w * cc.w;
                }
            }
            if (hh == 1) {
                #pragma unroll
                for (int u = 0; u < 16; ++u) acc2[u] *= 0.25f;
                if (s < NSITES - 1) {
                    #pragma unroll
                    for (int u = 0; u < 16; ++u) ETf[(q * 16 + u) * 64 + lane] = acc2[u];
                }
            }
            __syncthreads();
        }
    }
    {
        const int rR = xb[63], cR = xb[127];
        const float4 rr = *(const float4*)(right + rR * 256 + lane * 4);
        float partial = 0.f;
        #pragma unroll
        for (int u = 0; u < 16; ++u) {
            const int m = q * 16 + u;
            const float4 rcv = *(const float4*)(right + cR * 256 + m * 4);
            const float rv = rr.x * rcv.x + rr.y * rcv.y + rr.z * rcv.z + rr.w * rcv.w;
            partial += acc2[u] * rv;
        }
        #pragma unroll
        for (int off = 32; off > 0; off >>= 1)
            partial += __shfl_down(partial, off, 64);
        if (lane == 0) red[q] = partial;
        __syncthreads();
        if (t == 0) {
            const float rho = red[0] + red[1] + red[2] + red[3];
            out[2 * b + 0] = logf(fabsf(rho)) + (float)NSITES * LN4_F;
            out[2 * b + 1] = (rho < 0.f) ? PI_F : 0.f;
        }
    }
}

extern "C" void kernel_launch(void* const* d_in, const int* in_sizes, int n_in,
                              void* d_out, int out_size, void* d_ws, size_t ws_size,
                              hipStream_t stream) {
    const int*   x      = (const int*)  d_in[0];
    const float* left   = (const float*)d_in[1];
    const float* right  = (const float*)d_in[2];
    const float* middle = (const float*)d_in[3];
    float* out = (float*)d_out;

    const size_t A1_BYTES = (size_t)124 * 16384;   // 1.98 MB per operand buffer
    if (ws_size >= 2 * A1_BYTES) {
        unsigned char* a1f = (unsigned char*)d_ws;
        unsigned char* b2f = a1f + A1_BYTES;
        mpdo_prepass<<<dim3(1984), dim3(256), 0, stream>>>(middle, a1f, b2f);
        mpdo_mx<<<dim3(4096), dim3(256), 0, stream>>>(x, left, right, a1f, b2f, out);
    } else {
        mpdo_fp32<<<dim3(4096), dim3(256), 0, stream>>>(x, left, right, middle, out);
    }
}

// Round 11
// 550.010 us; speedup vs baseline: 1.3477x; 1.0358x over previous
//
#include <hip/hip_runtime.h>

// MPDO open-boundary contraction — MX-scaled fp8 MFMA (32x32x64).
// Per element: E0 = Lr·Lcᵀ; 62 steps E' = Σ_k Ar_kᵀ·E·Ac_k (×0.25 folded into
// packed Ac); rho = <E, Rr·Rcᵀ>; out = log(complex64(rho)) + 62·ln4.
//   P1: Tᵀ[l, jk] = Σ_i Eᵀ[l,i]·Ar[i,jk]   — one-shot mfma_scale (K=64 = full i)
//   P2: E'[j, m]  = Σ_kl T[j,kl]·Ac[kl,m]  — 4-chain mfma_scale
// Round-11 vs round-10 (546 µs steady, MfmaUtil 46, Occ 42.7):
//   Unified VGPR+AGPR file: combined live-set (~116) capped residency at
//   4 waves/SIMD in rounds 6-10 (Occ stuck ~43% independent of LDS).
//   Change: drop the next-step P1 prefetch (dead weight — the compiler's
//   vmcnt(0)-before-barrier drains it at the phase-1 barrier anyway; 32 regs
//   for nothing) and load bP1 at step start. Live set → ~84-100.
//   __launch_bounds__(256,5): combined cap 102 → 5 blocks/CU if it fits.
//   Tripwire: WRITE_SIZE must stay ~130 KB (round 9 spill showed 69 MB).
// LDS strides: ET row 72 B, TL j 264 B, k 64 B — all LDS ops at the
// 2-access/bank minimum. Fragments: A/B m|n = lane&31, k = 32*(lane>>5)+byte;
// C/D col=lane&31, row=(reg&3)+8*(reg>>2)+4*(lane>>5). Scales = 1.0 (0x7f).

#define NSITES 62
#define PI_F   3.14159265358979323846f
#define LN4_F  1.38629436111989061883f
#define ETS 72     // ET row stride, bytes
#define KSB 64     // TL k stride, bytes
#define JSB 264    // TL j stride, bytes = 4*KSB + 8 pad

typedef __attribute__((ext_vector_type(8)))  int   v8i;
typedef __attribute__((ext_vector_type(16))) float f32x16;

__device__ __forceinline__ float clamp8(float v) {
    return fminf(fmaxf(v, -448.f), 448.f);
}
// clamped pack (prepass / init — off critical path)
__device__ __forceinline__ int pk4c(float a, float b, float c, float d) {
    int r = __builtin_amdgcn_cvt_pk_fp8_f32(clamp8(a), clamp8(b), 0, false);
    r     = __builtin_amdgcn_cvt_pk_fp8_f32(clamp8(c), clamp8(d), r, true);
    return r;
}
// fast pack (main loop): values provably in fp8 range (growth cancelled by 0.25)
__device__ __forceinline__ int pk4(float a, float b, float c, float d) {
    int r = __builtin_amdgcn_cvt_pk_fp8_f32(a, b, 0, false);
    r     = __builtin_amdgcn_cvt_pk_fp8_f32(c, d, r, true);
    return r;
}
// 32-byte LDS fragment load as 4×b64 (8-aligned, conflict-free strides)
__device__ __forceinline__ v8i lds32(const unsigned char* p) {
    union { v8i v; unsigned long long u[4]; } r;
    r.u[0] = *(const unsigned long long*)(p);
    r.u[1] = *(const unsigned long long*)(p + 8);
    r.u[2] = *(const unsigned long long*)(p + 16);
    r.u[3] = *(const unsigned long long*)(p + 24);
    return r.v;
}
__device__ __forceinline__ f32x16 mfma_mx(v8i a, v8i b, f32x16 c) {
    // cbsz=0 (A fp8 e4m3), blgp=0 (B fp8), scales = 1.0 (0x7f bytes)
    return __builtin_amdgcn_mfma_scale_f32_32x32x64_f8f6f4(
        a, b, c, 0, 0, 0, 0x7f7f7f7f, 0, 0x7f7f7f7f);
}

// ---------------- prepass: middle (fp32) -> 32 B/lane fp8 fragments ----------------
// a1f: byte(sv, jt, lane, idx) = mid[sv][i = 32*(lane>>5)+idx][jk = jt*32+(lane&31)]
// b2f: byte(sv, mt*4+q, lane, idx) = 0.25*mid[sv][l = 32*(lane>>5)+idx][(mt*32+(lane&31))*4+q]
__global__ void mpdo_prepass(const float* __restrict__ mid,
                             unsigned char* __restrict__ a1f,
                             unsigned char* __restrict__ b2f)
{
    const int bb  = blockIdx.x;          // 0..1983
    const int buf = bb / 992;
    const int rem = bb % 992;
    const int sv  = rem >> 3;
    const int rg  = rem & 7;
    const int row = rg * 4 + (threadIdx.x >> 6);   // 0..31
    const int lane = threadIdx.x & 63;
    const int hh = lane >> 5, l5 = lane & 31;
    const int grp = row >> 2, seg = row & 3;       // grp: jt or mt*4+q
    const float* m0 = mid + (size_t)sv * 16384;

    float v[8];
    if (buf == 0) {
        const int jk = grp * 32 + l5;
        #pragma unroll
        for (int jj = 0; jj < 8; ++jj) {
            const int i = 32 * hh + 8 * seg + jj;
            v[jj] = m0[i * 256 + jk];
        }
    } else {
        const int mt = grp >> 2, q = grp & 3;
        const int col = (mt * 32 + l5) * 4 + q;
        #pragma unroll
        for (int jj = 0; jj < 8; ++jj) {
            const int l = 32 * hh + 8 * seg + jj;
            v[jj] = 0.25f * m0[l * 256 + col];     // fold per-step rescale
        }
    }
    int2 d;
    d.x = pk4c(v[0], v[1], v[2], v[3]);
    d.y = pk4c(v[4], v[5], v[6], v[7]);
    unsigned char* base = (buf == 0 ? a1f : b2f);
    *(int2*)(base + ((size_t)(sv * 8 + grp) * 64 + lane) * 32 + seg * 8) = d;
}

// ---------------- main kernel: 1 block per batch element ----------------
__global__ __launch_bounds__(256, 5)
void mpdo_mx(const int* __restrict__ x,
             const float* __restrict__ left,
             const float* __restrict__ right,
             const unsigned char* __restrict__ a1f,
             const unsigned char* __restrict__ b2f,
             float* __restrict__ out)
{
    __shared__ __align__(16) unsigned char ET[64 * ETS];  // ET[l][i] = E[i][l], fp8
    __shared__ __align__(16) unsigned char TL[64 * JSB];  // TL[j][k][l] = T, fp8
    __shared__ float red[4];

    const int t    = threadIdx.x;
    const int lane = t & 63;
    const int ln   = t & 31;
    const int h    = (t >> 5) & 1;
    const int w    = t >> 6;
    const int b    = blockIdx.x;
    const int* xb  = x + b * 128;

    // ---- init ET[l][i] = fp8( sum_k Lr[i,k]*Lc[l,k] ) ----
    {
        const int r0 = xb[0], c0 = xb[64];
        const int l = t >> 2, cq = t & 3;
        const float4 lc = *(const float4*)(left + c0 * 256 + l * 4);
        #pragma unroll
        for (int ib = 0; ib < 4; ++ib) {
            float vv[4];
            #pragma unroll
            for (int u = 0; u < 4; ++u) {
                const int i = cq * 16 + ib * 4 + u;
                const float4 lr = *(const float4*)(left + r0 * 256 + i * 4);
                vv[u] = lr.x * lc.x + lr.y * lc.y + lr.z * lc.z + lr.w * lc.w;
            }
            *(int*)&ET[l * ETS + cq * 16 + ib * 4] = pk4c(vv[0], vv[1], vv[2], vv[3]);
        }
    }

    const int jt2 = w >> 1;   // phase-2 j-tile
    const int mt  = w & 1;    // phase-2 m-tile

    // const-zero C operand — lives across the loop, never written
    f32x16 z16;
    #pragma unroll
    for (int r = 0; r < 16; ++r) z16[r] = 0.f;

    __syncthreads();

    f32x16 acc2;

    #pragma unroll 1
    for (int s = 0; s < NSITES; ++s) {
        // ---- issue all of this step's global loads up front ----
        // bP2 is consumed after the phase-1 barrier (fully covered);
        // bP1 is consumed after the two aF ds_reads (~120 cyc cover).
        const unsigned char* B2 = b2f + (size_t)(s * 2 + xb[65 + s]) * 16384;
        v8i bP2[4];
        #pragma unroll
        for (int q = 0; q < 4; ++q)
            bP2[q] = *(const v8i*)(B2 + ((size_t)(mt * 4 + q) * 64 + lane) * 32);

        const unsigned char* A1 = a1f + (size_t)(s * 2 + xb[1 + s]) * 16384;
        const v8i bP1a = *(const v8i*)(A1 + ((size_t)(2 * w + 0) * 64 + lane) * 32);
        const v8i bP1b = *(const v8i*)(A1 + ((size_t)(2 * w + 1) * 64 + lane) * 32);

        // ---- phase 1 (two jl-halves, capped live registers) ----
        const v8i aF0 = lds32(&ET[(0  + ln) * ETS + 32 * h]);
        const v8i aF1 = lds32(&ET[(32 + ln) * ETS + 32 * h]);
        {
            const f32x16 t0 = mfma_mx(aF0, bP1a, z16);
            const f32x16 t1 = mfma_mx(aF1, bP1a, z16);
            const int jk = (2 * w + 0) * 32 + ln;
            const unsigned base = (jk >> 2) * JSB + (jk & 3) * KSB + 4 * h;
            #pragma unroll
            for (int g = 0; g < 4; ++g) {
                *(int*)&TL[base + 8 * g]      = pk4(t0[4*g], t0[4*g+1], t0[4*g+2], t0[4*g+3]);
                *(int*)&TL[base + 32 + 8 * g] = pk4(t1[4*g], t1[4*g+1], t1[4*g+2], t1[4*g+3]);
            }
        }
        {
            const f32x16 t0 = mfma_mx(aF0, bP1b, z16);
            const f32x16 t1 = mfma_mx(aF1, bP1b, z16);
            const int jk = (2 * w + 1) * 32 + ln;
            const unsigned base = (jk >> 2) * JSB + (jk & 3) * KSB + 4 * h;
            #pragma unroll
            for (int g = 0; g < 4; ++g) {
                *(int*)&TL[base + 8 * g]      = pk4(t0[4*g], t0[4*g+1], t0[4*g+2], t0[4*g+3]);
                *(int*)&TL[base + 32 + 8 * g] = pk4(t1[4*g], t1[4*g+1], t1[4*g+2], t1[4*g+3]);
            }
        }
        __syncthreads();

        // ---- phase 2: E'[j,m] = Σ_q Σ_l T[j,q,l]·(0.25·Ac)[l, m*4+q] ----
        acc2 = mfma_mx(lds32(&TL[(jt2 * 32 + ln) * JSB + 0 * KSB + 32 * h]), bP2[0], z16);
        #pragma unroll
        for (int q = 1; q < 4; ++q)
            acc2 = mfma_mx(lds32(&TL[(jt2 * 32 + ln) * JSB + q * KSB + 32 * h]), bP2[q], acc2);

        if (s < NSITES - 1) {
            // write E' back: ET[m][j] = E'[j][m], 4 fp8 per b32
            const unsigned base = (mt * 32 + ln) * ETS + jt2 * 32 + 4 * h;
            #pragma unroll
            for (int g = 0; g < 4; ++g)
                *(int*)&ET[base + 8 * g] =
                    pk4(acc2[4 * g], acc2[4 * g + 1], acc2[4 * g + 2], acc2[4 * g + 3]);
        }
        __syncthreads();
    }

    // ---- final: rho = sum E_final[j,m] * R[j,m], R = Rr·Rcᵀ (fp32) ----
    {
        const int rR = xb[63], cR = xb[127];
        const int m = mt * 32 + ln;
        const float4 rc = *(const float4*)(right + cR * 256 + m * 4);
        float partial = 0.f;
        #pragma unroll
        for (int r = 0; r < 16; ++r) {
            const int j = jt2 * 32 + (r & 3) + 8 * (r >> 2) + 4 * h;
            const float4 rr = *(const float4*)(right + rR * 256 + j * 4);
            const float Rv = rr.x * rc.x + rr.y * rc.y + rr.z * rc.z + rr.w * rc.w;
            partial += acc2[r] * Rv;
        }
        #pragma unroll
        for (int off = 32; off > 0; off >>= 1)
            partial += __shfl_down(partial, off, 64);
        if (lane == 0) red[w] = partial;
        __syncthreads();
        if (t == 0) {
            const float rho = red[0] + red[1] + red[2] + red[3];
            out[2 * b + 0] = logf(fabsf(rho)) + (float)NSITES * LN4_F;
            out[2 * b + 1] = (rho < 0.f) ? PI_F : 0.f;
        }
    }
}

// ---------------- fp32 fallback if ws too small ----------------
__global__ __launch_bounds__(256, 3)
void mpdo_fp32(const int* __restrict__ x, const float* __restrict__ left,
               const float* __restrict__ right, const float* __restrict__ middle,
               float* __restrict__ out)
{
    __shared__ float ETf[64 * 64];
    __shared__ float TRI[32 * 256];
    __shared__ float red[4];
    const int t = threadIdx.x, lane = t & 63, q = t >> 6, b = blockIdx.x;
    const int* xb = x + b * 128;
    {
        const int r0 = xb[0], c0 = xb[64];
        const float4 lr = *(const float4*)(left + r0 * 256 + lane * 4);
        #pragma unroll
        for (int u = 0; u < 16; ++u) {
            const int bb = q * 16 + u;
            const float4 lc = *(const float4*)(left + c0 * 256 + bb * 4);
            ETf[bb * 64 + lane] = lr.x * lc.x + lr.y * lc.y + lr.z * lc.z + lr.w * lc.w;
        }
    }
    __syncthreads();
    float acc2[16];
    for (int s = 0; s < NSITES; ++s) {
        const int r = xb[1 + s], c = xb[65 + s];
        const float* Ar = middle + (size_t)s * 32768 + (size_t)r * 16384;
        const float* Ac = middle + (size_t)s * 32768 + (size_t)c * 16384;
        #pragma unroll
        for (int u = 0; u < 16; ++u) acc2[u] = 0.f;
        float acc[4][16];
        #pragma unroll
        for (int j = 0; j < 4; ++j)
            #pragma unroll
            for (int u = 0; u < 16; ++u) acc[j][u] = 0.f;
        #pragma unroll 1
        for (int i4 = 0; i4 < 16; ++i4) {
            const float4 a0 = *(const float4*)(Ar + (i4 * 4 + 0) * 256 + lane * 4);
            const float4 a1 = *(const float4*)(Ar + (i4 * 4 + 1) * 256 + lane * 4);
            const float4 a2 = *(const float4*)(Ar + (i4 * 4 + 2) * 256 + lane * 4);
            const float4 a3 = *(const float4*)(Ar + (i4 * 4 + 3) * 256 + lane * 4);
            #pragma unroll
            for (int hh = 0; hh < 2; ++hh) {
                #pragma unroll
                for (int lp = 0; lp < 8; ++lp) {
                    const int lg = hh * 32 + q * 8 + lp;
                    const float4 e = *(const float4*)&ETf[lg * 64 + i4 * 4];
                    const int li = hh * 8 + lp;
                    acc[0][li] += a0.x * e.x + a1.x * e.y + a2.x * e.z + a3.x * e.w;
                    acc[1][li] += a0.y * e.x + a1.y * e.y + a2.y * e.z + a3.y * e.w;
                    acc[2][li] += a0.z * e.x + a1.z * e.y + a2.z * e.z + a3.z * e.w;
                    acc[3][li] += a0.w * e.x + a1.w * e.y + a2.w * e.z + a3.w * e.w;
                }
            }
        }
        #pragma unroll 1
        for (int hh = 0; hh < 2; ++hh) {
            #pragma unroll
            for (int lp = 0; lp < 8; ++lp) {
                const int li = hh * 8 + lp;
                const float4 v = make_float4(acc[0][li], acc[1][li], acc[2][li], acc[3][li]);
                *(float4*)&TRI[(q * 8 + lp) * 256 + lane * 4] = v;
            }
            __syncthreads();
            const float* Acb = Ac + hh * 32 * 256 + q * 64;
            #pragma unroll 1
            for (int ll = 0; ll < 32; ++ll) {
                const float4 tr = *(const float4*)&TRI[ll * 256 + lane * 4];
                const float* bp = Acb + ll * 256;
                #pragma unroll
                for (int u = 0; u < 16; ++u) {
                    const float4 cc = *(const float4*)(bp + u * 4);
                    acc2[u] += tr.x * cc.x + tr.y * cc.y + tr.z * cc.z + tr.w * cc.w;
                }
            }
            if (hh == 1) {
                #pragma unroll
                for (int u = 0; u < 16; ++u) acc2[u] *= 0.25f;
                if (s < NSITES - 1) {
                    #pragma unroll
                    for (int u = 0; u < 16; ++u) ETf[(q * 16 + u) * 64 + lane] = acc2[u];
                }
            }
            __syncthreads();
        }
    }
    {
        const int rR = xb[63], cR = xb[127];
        const float4 rr = *(const float4*)(right + rR * 256 + lane * 4);
        float partial = 0.f;
        #pragma unroll
        for (int u = 0; u < 16; ++u) {
            const int m = q * 16 + u;
            const float4 rcv = *(const float4*)(right + cR * 256 + m * 4);
            const float rv = rr.x * rcv.x + rr.y * rcv.y + rr.z * rcv.z + rr.w * rcv.w;
            partial += acc2[u] * rv;
        }
        #pragma unroll
        for (int off = 32; off > 0; off >>= 1)
            partial += __shfl_down(partial, off, 64);
        if (lane == 0) red[q] = partial;
        __syncthreads();
        if (t == 0) {
            const float rho = red[0] + red[1] + red[2] + red[3];
            out[2 * b + 0] = logf(fabsf(rho)) + (float)NSITES * LN4_F;
            out[2 * b + 1] = (rho < 0.f) ? PI_F : 0.f;
        }
    }
}

extern "C" void kernel_launch(void* const* d_in, const int* in_sizes, int n_in,
                              void* d_out, int out_size, void* d_ws, size_t ws_size,
                              hipStream_t stream) {
    const int*   x      = (const int*)  d_in[0];
    const float* left   = (const float*)d_in[1];
    const float* right  = (const float*)d_in[2];
    const float* middle = (const float*)d_in[3];
    float* out = (float*)d_out;

    const size_t A1_BYTES = (size_t)124 * 16384;   // 1.98 MB per operand buffer
    if (ws_size >= 2 * A1_BYTES) {
        unsigned char* a1f = (unsigned char*)d_ws;
        unsigned char* b2f = a1f + A1_BYTES;
        mpdo_prepass<<<dim3(1984), dim3(256), 0, stream>>>(middle, a1f, b2f);
        mpdo_mx<<<dim3(4096), dim3(256), 0, stream>>>(x, left, right, a1f, b2f, out);
    } else {
        mpdo_fp32<<<dim3(4096), dim3(256), 0, stream>>>(x, left, right, middle, out);
    }
}